// Round 1
// baseline (9358.376 us; speedup 1.0000x reference)
//
#include <hip/hip_runtime.h>
#include <hip/hip_bf16.h>

// MSAColumnAttention  (S=512 seq, R=384 res, C_M=256, 8 heads x C=32)
// R0 baseline: fp32 VALU compute, bf16 storage for xhat/Q/K/V/G (tests the
// numerics the future MFMA version needs), fp32 accumulation throughout.
//
// ws layout (bytes), total = 252,710,912:
//   [0, 1MB)        Wall  : folded weights  [8 heads][128 rows(q,k,v,g x32)][256] f32
//   [1MB, +4KB)     ball  : folded biases   [8][128] f32
//   [+, +50.3MB)    qkvg  : one head's projections [196608 rows][128] bf16 (reused per head)
//   [+, +201.3MB)   cat   : gated attention outputs [196608][256] f32

#define S_DIM 512
#define R_DIM 384
#define CM    256
#define NH    8
#define NROWS (S_DIM*R_DIM)

typedef unsigned short u16;
typedef unsigned int   u32;

#define PROJ_LDS (128*256*2 + 64*256*2)   // 98304  (w bf16 + xhat tile bf16)
#define ATTN_LDS (512*128*2 + 2*512*4)    // 135168 (qkvg tile bf16 + mcol/ivd f32)

__device__ __forceinline__ float lo16(u32 u){ return __uint_as_float(u << 16); }
__device__ __forceinline__ float hi16(u32 u){ return __uint_as_float(u & 0xffff0000u); }
__device__ __forceinline__ u16 f2bf(float f){
  u32 u = __float_as_uint(f);
  return (u16)((u + 0x7fffu + ((u >> 16) & 1u)) >> 16);   // RNE
}
__device__ __forceinline__ u32 pk2(float a, float b){
  return (u32)f2bf(a) | ((u32)f2bf(b) << 16);
}
__device__ __forceinline__ void unp8(uint4 u, float* f){
  f[0]=lo16(u.x); f[1]=hi16(u.x); f[2]=lo16(u.y); f[3]=hi16(u.y);
  f[4]=lo16(u.z); f[5]=hi16(u.z); f[6]=lo16(u.w); f[7]=hi16(u.w);
}

// ---------------------------------------------------------------- fold_w ----
// Wall[h][row][m] = Wsrc[h][c][m] * ln_w[h][m];  ball[h][row] = dot(ln_b[h], Wsrc[h][c])
// row = mat*32 + c, mat in {q,k,v,g}. 1024 blocks x 64 threads.
__global__ void fold_w(const float* __restrict__ lnw, const float* __restrict__ lnb,
                       const float* __restrict__ Wq, const float* __restrict__ Wk,
                       const float* __restrict__ Wv, const float* __restrict__ Wg,
                       float* __restrict__ Wall, float* __restrict__ ball){
  int blk = blockIdx.x;           // h*128 + row
  int h = blk >> 7, row = blk & 127;
  int mat = row >> 5, c = row & 31;
  const float* Ws = (mat==0?Wq: mat==1?Wk: mat==2?Wv:Wg) + (size_t)(h*32 + c)*CM;
  int t = threadIdx.x;            // 64 threads, 4 elems each
  float4 w4 = ((const float4*)Ws)[t];
  float4 l4 = ((const float4*)(lnw + (size_t)h*CM))[t];
  float4 b4 = ((const float4*)(lnb + (size_t)h*CM))[t];
  float4 o4 = make_float4(w4.x*l4.x, w4.y*l4.y, w4.z*l4.z, w4.w*l4.w);
  ((float4*)(Wall + (size_t)blk*CM))[t] = o4;
  float p = w4.x*b4.x + w4.y*b4.y + w4.z*b4.z + w4.w*b4.w;
  #pragma unroll
  for(int off=32; off; off>>=1) p += __shfl_down(p, off);
  if(t==0) ball[blk] = p;
}

// ---------------------------------------------------------------- proj_h ----
// One block = 64 consecutive flat rows n=(r*512+s). Fused LN (shared stats across
// heads; ln_w/ln_b folded into Wall/ball) + 64x128 GEMM over K=256.
// qkvg[n][col] bf16, col = mat*32+c; g is sigmoid-ed at write.
__global__ __launch_bounds__(256,1) void proj_h(const float* __restrict__ msa,
      const float* __restrict__ Wall, const float* __restrict__ ball,
      u16* __restrict__ qkvg, int h){
  extern __shared__ char smem[];
  u16* wl = (u16*)smem;                    // [128][256] bf16
  u16* xh = (u16*)(smem + 128*256*2);      // [64][256]  bf16
  const int tid = threadIdx.x;
  // stage folded weights for this head (fp32 -> bf16)
  const float* Wh = Wall + (size_t)h*128*CM;
  #pragma unroll 4
  for(int i=0;i<32;i++){
    int e = i*1024 + tid*4;
    float4 w4 = *(const float4*)(Wh + e);
    u16* dst = wl + e;                     // row-major [128][256], e already linear
    dst[0]=f2bf(w4.x); dst[1]=f2bf(w4.y); dst[2]=f2bf(w4.z); dst[3]=f2bf(w4.w);
  }
  // LayerNorm: 4 threads per row, 64 floats each
  const int n0 = blockIdx.x * 64;
  {
    int i = tid >> 2, p = tid & 3;
    int n = n0 + i, r = n >> 9, s = n & 511;
    const float* src = msa + ((size_t)s*R_DIM + r)*CM + p*64;
    float x[64]; float sum=0.f, sq=0.f;
    #pragma unroll
    for(int j=0;j<64;j+=4){
      float4 v = *(const float4*)(src + j);
      x[j]=v.x; x[j+1]=v.y; x[j+2]=v.z; x[j+3]=v.w;
      sum += v.x+v.y+v.z+v.w;
      sq  += v.x*v.x + v.y*v.y + v.z*v.z + v.w*v.w;
    }
    sum += __shfl_xor(sum,1); sum += __shfl_xor(sum,2);
    sq  += __shfl_xor(sq ,1); sq  += __shfl_xor(sq ,2);
    float mu = sum * (1.f/256.f);
    float var = sq * (1.f/256.f) - mu*mu;
    float rs = rsqrtf(var + 1e-5f);
    u16* xrow = xh + i*256 + p*64;
    #pragma unroll
    for(int j=0;j<64;j+=2)
      *(u32*)(xrow + j) = pk2((x[j]-mu)*rs, (x[j+1]-mu)*rs);
  }
  __syncthreads();
  // GEMM: thread -> 4 cols x 8 rows
  const int c0 = (tid & 31) * 4;
  const int r0 = (tid >> 5) * 8;
  float acc[4][8];
  #pragma unroll
  for(int a=0;a<4;a++)
    #pragma unroll
    for(int k=0;k<8;k++) acc[a][k]=0.f;
  for(int m=0;m<256;m+=8){
    float wf[4][8];
    #pragma unroll
    for(int a=0;a<4;a++) unp8(*(const uint4*)(wl + (c0+a)*256 + m), wf[a]);
    #pragma unroll
    for(int k=0;k<8;k++){
      float xf[8]; unp8(*(const uint4*)(xh + (r0+k)*256 + m), xf);
      #pragma unroll
      for(int a=0;a<4;a++){
        float* w = wf[a];
        acc[a][k] += w[0]*xf[0] + w[1]*xf[1] + w[2]*xf[2] + w[3]*xf[3]
                   + w[4]*xf[4] + w[5]*xf[5] + w[6]*xf[6] + w[7]*xf[7];
      }
    }
  }
  const float* bl = ball + h*128;
  #pragma unroll
  for(int a=0;a<4;a++){
    int cc = c0 + a;
    float b = bl[cc];
    bool isg = (cc >> 5) == 3;
    #pragma unroll
    for(int k=0;k<8;k++){
      float v = acc[a][k] + b;
      if(isg) v = 1.f/(1.f + __expf(-v));   // sigmoid gate
      acc[a][k] = v;
    }
  }
  #pragma unroll
  for(int k=0;k<8;k++){
    u32 w0 = pk2(acc[0][k], acc[1][k]);
    u32 w1 = pk2(acc[2][k], acc[3][k]);
    *(uint2*)(qkvg + (size_t)(n0 + r0 + k)*128 + c0) = make_uint2(w0, w1);
  }
}

// ---------------------------------------------------------------- attn_h ----
// One block per column r. Q/K/V/G LDS-resident (bf16). Softmax over axis s
// (the reference's axis=-2): per-t online max/denominator, then
// o[s,c] = g[s,c] * sum_t exp(l[s,t]-m[t])/D[t] * v[t,c].
__global__ __launch_bounds__(256,1) void attn_h(const u16* __restrict__ qkvg,
                                                float* __restrict__ cat, int h){
  extern __shared__ char smem[];
  u16* T = (u16*)smem;                       // [512][128]: q|k|v|g x32 each
  float* mcol = (float*)(smem + 512*128*2);  // [512]
  float* ivd  = mcol + 512;                  // [512]
  const int r = blockIdx.x, tid = threadIdx.x;
  { const uint4* src = (const uint4*)(qkvg + (size_t)r*512*128);
    uint4* dst = (uint4*)T;
    #pragma unroll
    for(int i=0;i<32;i++) dst[i*256+tid] = src[i*256+tid]; }
  __syncthreads();
  const float scale = 0.17677669529663687f;  // 1/sqrt(32)
  // ---- pass 1: per-t (t0=tid, t1=tid+256) online max & denom over s
  float k0[32], k1[32];
  #pragma unroll
  for(int i=0;i<4;i++){
    unp8(((const uint4*)(T + tid*128 + 32))[i],       k0 + i*8);
    unp8(((const uint4*)(T + (tid+256)*128 + 32))[i], k1 + i*8);
  }
  float m0=-1e30f, d0=0.f, m1=-1e30f, d1=0.f;
  for(int s=0;s<512;s++){
    float q[32];
    #pragma unroll
    for(int i=0;i<4;i++) unp8(((const uint4*)(T + s*128))[i], q + i*8);
    float a0=0.f,a1=0.f,a2=0.f,a3=0.f,b0=0.f,b1=0.f,b2=0.f,b3=0.f;
    #pragma unroll
    for(int j=0;j<32;j+=4){
      a0 += q[j+0]*k0[j+0]; a1 += q[j+1]*k0[j+1];
      a2 += q[j+2]*k0[j+2]; a3 += q[j+3]*k0[j+3];
      b0 += q[j+0]*k1[j+0]; b1 += q[j+1]*k1[j+1];
      b2 += q[j+2]*k1[j+2]; b3 += q[j+3]*k1[j+3];
    }
    float l0 = ((a0+a1)+(a2+a3))*scale;
    float l1 = ((b0+b1)+(b2+b3))*scale;
    float n0 = fmaxf(m0,l0); d0 = d0*__expf(m0-n0) + __expf(l0-n0); m0 = n0;
    float n1 = fmaxf(m1,l1); d1 = d1*__expf(m1-n1) + __expf(l1-n1); m1 = n1;
  }
  mcol[tid]     = m0; ivd[tid]     = 1.f/d0;
  mcol[tid+256] = m1; ivd[tid+256] = 1.f/d1;
  __syncthreads();
  // ---- pass 2: per-s (s0=tid, s1=tid+256), recompute logits, accumulate AV
  float q0[32], q1[32], o0[32], o1[32];
  #pragma unroll
  for(int i=0;i<4;i++){
    unp8(((const uint4*)(T + tid*128))[i],       q0 + i*8);
    unp8(((const uint4*)(T + (tid+256)*128))[i], q1 + i*8);
  }
  #pragma unroll
  for(int j=0;j<32;j++){ o0[j]=0.f; o1[j]=0.f; }
  for(int t=0;t<512;t++){
    float kk[32], vv[32];
    #pragma unroll
    for(int i=0;i<4;i++){
      unp8(((const uint4*)(T + t*128 + 32))[i], kk + i*8);
      unp8(((const uint4*)(T + t*128 + 64))[i], vv + i*8);
    }
    float a0=0.f,a1=0.f,a2=0.f,a3=0.f,b0=0.f,b1=0.f,b2=0.f,b3=0.f;
    #pragma unroll
    for(int j=0;j<32;j+=4){
      a0 += q0[j+0]*kk[j+0]; a1 += q0[j+1]*kk[j+1];
      a2 += q0[j+2]*kk[j+2]; a3 += q0[j+3]*kk[j+3];
      b0 += q1[j+0]*kk[j+0]; b1 += q1[j+1]*kk[j+1];
      b2 += q1[j+2]*kk[j+2]; b3 += q1[j+3]*kk[j+3];
    }
    float l0 = ((a0+a1)+(a2+a3))*scale;
    float l1 = ((b0+b1)+(b2+b3))*scale;
    float mc = mcol[t], iv = ivd[t];
    float w0 = __expf(l0 - mc)*iv;
    float w1 = __expf(l1 - mc)*iv;
    #pragma unroll
    for(int j=0;j<32;j++){ o0[j] += w0*vv[j]; o1[j] += w1*vv[j]; }
  }
  // gate + store (cat fp32 for accuracy margin)
  float g0[32], g1[32];
  #pragma unroll
  for(int i=0;i<4;i++){
    unp8(((const uint4*)(T + tid*128 + 96))[i],       g0 + i*8);
    unp8(((const uint4*)(T + (tid+256)*128 + 96))[i], g1 + i*8);
  }
  float* dst0 = cat + (size_t)(r*512 + tid)*256 + h*32;
  float* dst1 = cat + (size_t)(r*512 + tid + 256)*256 + h*32;
  #pragma unroll
  for(int j=0;j<32;j+=4){
    *(float4*)(dst0+j) = make_float4(o0[j]*g0[j], o0[j+1]*g0[j+1],
                                     o0[j+2]*g0[j+2], o0[j+3]*g0[j+3]);
    *(float4*)(dst1+j) = make_float4(o1[j]*g1[j], o1[j+1]*g1[j+1],
                                     o1[j+2]*g1[j+2], o1[j+3]*g1[j+3]);
  }
}

// --------------------------------------------------------------- outproj ----
// out[s][r][m] = sum_d cat[n][d]*out_W[m][d] + out_b[m],  n = r*512+s.
// Block = 32 rows; thread -> cols {m, m+128} x 16 rows; weights from global (L2).
__global__ __launch_bounds__(256) void outproj(const float* __restrict__ cat,
      const float* __restrict__ oW, const float* __restrict__ ob,
      float* __restrict__ out){
  __shared__ float ct[32*256];   // 32 KB
  const int tid = threadIdx.x;
  const int n0 = blockIdx.x * 32;
  { const float4* s4 = (const float4*)(cat + (size_t)n0*256);
    float4* d4 = (float4*)ct;
    #pragma unroll
    for(int i=0;i<8;i++) d4[i*256+tid] = s4[i*256+tid]; }
  __syncthreads();
  const int m0 = tid & 127;
  const int rg = tid >> 7;
  const float* w0p = oW + (size_t)m0*CM;
  const float* w1p = oW + (size_t)(m0+128)*CM;
  float acc0[16], acc1[16];
  #pragma unroll
  for(int k2=0;k2<16;k2++){ acc0[k2]=0.f; acc1[k2]=0.f; }
  for(int d=0; d<256; d+=8){
    float4 wa = *(const float4*)(w0p + d), wb = *(const float4*)(w0p + d + 4);
    float4 wc = *(const float4*)(w1p + d), wd = *(const float4*)(w1p + d + 4);
    #pragma unroll
    for(int k2=0;k2<16;k2++){
      const float* cr = ct + (rg*16 + k2)*256 + d;
      float4 ca = *(const float4*)(cr), cb = *(const float4*)(cr + 4);
      acc0[k2] += wa.x*ca.x + wa.y*ca.y + wa.z*ca.z + wa.w*ca.w
                + wb.x*cb.x + wb.y*cb.y + wb.z*cb.z + wb.w*cb.w;
      acc1[k2] += wc.x*ca.x + wc.y*ca.y + wc.z*ca.z + wc.w*ca.w
                + wd.x*cb.x + wd.y*cb.y + wd.z*cb.z + wd.w*cb.w;
    }
  }
  const float bb0 = ob[m0], bb1 = ob[m0+128];
  #pragma unroll
  for(int k2=0;k2<16;k2++){
    int n = n0 + rg*16 + k2;
    int rr = n >> 9, ss = n & 511;
    float* o = out + ((size_t)ss*R_DIM + rr)*CM;
    o[m0]     = acc0[k2] + bb0;
    o[m0+128] = acc1[k2] + bb1;
  }
}

// ------------------------------------------------------------------ host ----
extern "C" void kernel_launch(void* const* d_in, const int* in_sizes, int n_in,
                              void* d_out, int out_size, void* d_ws, size_t ws_size,
                              hipStream_t stream){
  const float* msa = (const float*)d_in[0];
  const float* lnw = (const float*)d_in[1];
  const float* lnb = (const float*)d_in[2];
  const float* Wq  = (const float*)d_in[3];
  const float* Wk  = (const float*)d_in[4];
  const float* Wv  = (const float*)d_in[5];
  const float* Wg  = (const float*)d_in[6];
  const float* oW  = (const float*)d_in[7];
  const float* ob  = (const float*)d_in[8];
  float* out = (float*)d_out;

  char* ws = (char*)d_ws;
  float* Wall = (float*)ws;                                        // 1 MB
  float* ball = (float*)(ws + (size_t)1048576);                    // 4 KB
  u16*   qkvg = (u16*)(ws + (size_t)1048576 + 4096);               // 50.3 MB
  float* cat  = (float*)(ws + (size_t)1048576 + 4096
                            + (size_t)NROWS*128*2);                // 201.3 MB
  // total ws need: 252,710,912 B

  hipFuncSetAttribute((const void*)proj_h, hipFuncAttributeMaxDynamicSharedMemorySize, PROJ_LDS);
  hipFuncSetAttribute((const void*)attn_h, hipFuncAttributeMaxDynamicSharedMemorySize, ATTN_LDS);

  fold_w<<<dim3(1024), dim3(64), 0, stream>>>(lnw, lnb, Wq, Wk, Wv, Wg, Wall, ball);
  for(int h=0; h<NH; h++){
    proj_h<<<dim3(NROWS/64), dim3(256), PROJ_LDS, stream>>>(msa, Wall, ball, qkvg, h);
    attn_h<<<dim3(R_DIM),    dim3(256), ATTN_LDS, stream>>>(qkvg, cat, h);
  }
  outproj<<<dim3(NROWS/32), dim3(256), 0, stream>>>(cat, oW, ob, out);
}

// Round 2
// 1674.994 us; speedup vs baseline: 5.5871x; 5.5871x over previous
//
#include <hip/hip_runtime.h>
#include <hip/hip_bf16.h>

// MSAColumnAttention — R1: MFMA everywhere, all heads batched.
// Pipeline: prep_w -> ln_xhat (LN once, shared stats) -> attn_fused (proj+QK+softmax_s+PV+gate,
// one block per (r,h)) -> outproj (bf16 GEMM, W split hi/lo).
//
// MFMA 16x16x32 bf16 layouts (m89-consistent):
//   A[m][k]: lane(g,i)=g*16+i holds row m=i,  k=8g+e (e=0..7, bf16x8)
//   B[k][n]: lane(g,i) holds col n=i,         k=8g+e
//   D[m][n]: lane(g,i) holds col n=i, rows m=4g+q (q=reg 0..3)
//
// ws layout (total 202,117,120 B < 252.7 MB proven in R0):
//   Wallbf [8][128][256] bf16 @ 0
//   ball   [1024] f32        @ 524288
//   oWhi   [256][256] bf16   @ 528384
//   oWlo   [256][256] bf16   @ 659456
//   xhat   [196608][256] bf16@ 790528
//   obuf   [196608][256] bf16@ 101453824   (gated attention output)

#define S_DIM 512
#define R_DIM 384
#define CM    256
#define NH    8
#define NROWS (S_DIM*R_DIM)

typedef unsigned short u16;
typedef unsigned int   u32;
typedef short bf16x8 __attribute__((ext_vector_type(8)));
typedef float f32x4  __attribute__((ext_vector_type(4)));

#define MFMA16(a,b,c) __builtin_amdgcn_mfma_f32_16x16x32_bf16((a),(b),(c),0,0,0)

__device__ __forceinline__ float b2f(u16 x){ return __uint_as_float(((u32)x) << 16); }
__device__ __forceinline__ u16 f2bf(float f){
  u32 u = __float_as_uint(f);
  return (u16)((u + 0x7fffu + ((u >> 16) & 1u)) >> 16);   // RNE
}
__device__ __forceinline__ u32 pk2(float a, float b){
  return (u32)f2bf(a) | ((u32)f2bf(b) << 16);
}

// ---------------------------------------------------------------- prep_w ----
// blocks 0..1023: fold ln into Wq/Wk/Wv/Wg -> Wallbf bf16, ball f32.
// blocks 1024..1279: split out_W into hi/lo bf16.
__global__ void prep_w(const float* __restrict__ lnw, const float* __restrict__ lnb,
                       const float* __restrict__ Wq, const float* __restrict__ Wk,
                       const float* __restrict__ Wv, const float* __restrict__ Wg,
                       const float* __restrict__ oW,
                       float* __restrict__ ball, u16* __restrict__ Wallbf,
                       u16* __restrict__ oWhi, u16* __restrict__ oWlo){
  int blk = blockIdx.x, t = threadIdx.x;
  if (blk < 1024){
    int h = blk >> 7, row = blk & 127, mat = row >> 5, c = row & 31;
    const float* Ws = (mat==0?Wq: mat==1?Wk: mat==2?Wv:Wg) + (size_t)(h*32+c)*CM;
    float4 w4 = ((const float4*)Ws)[t];
    float4 l4 = ((const float4*)(lnw + (size_t)h*CM))[t];
    float4 b4 = ((const float4*)(lnb + (size_t)h*CM))[t];
    ((uint2*)(Wallbf + (size_t)blk*CM))[t] =
        make_uint2(pk2(w4.x*l4.x, w4.y*l4.y), pk2(w4.z*l4.z, w4.w*l4.w));
    float p = w4.x*b4.x + w4.y*b4.y + w4.z*b4.z + w4.w*b4.w;
    #pragma unroll
    for(int off=32; off; off>>=1) p += __shfl_down(p, off);
    if(t==0) ball[blk] = p;
  } else {
    int m = blk - 1024;
    float4 w4 = ((const float4*)(oW + (size_t)m*CM))[t];
    u16 h0=f2bf(w4.x), h1=f2bf(w4.y), h2=f2bf(w4.z), h3=f2bf(w4.w);
    u16 l0=f2bf(w4.x-b2f(h0)), l1=f2bf(w4.y-b2f(h1));
    u16 l2=f2bf(w4.z-b2f(h2)), l3=f2bf(w4.w-b2f(h3));
    ((uint2*)(oWhi + (size_t)m*CM))[t] = make_uint2((u32)h0|((u32)h1<<16), (u32)h2|((u32)h3<<16));
    ((uint2*)(oWlo + (size_t)m*CM))[t] = make_uint2((u32)l0|((u32)l1<<16), (u32)l2|((u32)l3<<16));
  }
}

// ---------------------------------------------------------------- ln_xhat ----
// xhat[n][m] bf16, n = r*512+s. 4 threads/row, stats in fp32.
__global__ __launch_bounds__(256) void ln_xhat(const float* __restrict__ msa,
                                               u16* __restrict__ xhat){
  const int tid = threadIdx.x;
  const int n0 = blockIdx.x*64;
  const int i = tid >> 2, p = tid & 3;
  const int n = n0 + i, rr = n >> 9, s = n & 511;
  const float* src = msa + ((size_t)s*R_DIM + rr)*CM + p*64;
  float x[64]; float sum=0.f, sq=0.f;
  #pragma unroll
  for(int j=0;j<64;j+=4){
    float4 v = *(const float4*)(src + j);
    x[j]=v.x; x[j+1]=v.y; x[j+2]=v.z; x[j+3]=v.w;
    sum += v.x+v.y+v.z+v.w;
    sq  += v.x*v.x + v.y*v.y + v.z*v.z + v.w*v.w;
  }
  sum += __shfl_xor(sum,1); sum += __shfl_xor(sum,2);
  sq  += __shfl_xor(sq,1);  sq  += __shfl_xor(sq,2);
  float mu = sum*(1.f/256.f);
  float rs = rsqrtf(sq*(1.f/256.f) - mu*mu + 1e-5f);
  u16* dst = xhat + (size_t)n*CM + p*64;
  #pragma unroll
  for(int j=0;j<64;j+=2)
    *(u32*)(dst + j) = pk2((x[j]-mu)*rs, (x[j+1]-mu)*rs);
}

// --------------------------------------------------------------- attn_fused ----
// One block per (r,h): 512 threads = 8 waves.
//   proj : wave w -> out cols 16w..16w+15 of [Q|K|V|G]; Q/K/V/G -> LDS (bf16, swizzled).
//   A    : d[t] = sum_s exp(scale*l[s,t]) (no max: logits ~±0.5 by construction); ivd=1/d.
//   B    : O[s,c] = sum_t exp(scale*l)*ivd[t] * V[t,c] via P->LDS bf16 repack; gate; store.
// LDS rows of Q/K/V/G are 64 B; 16B-chunk swizzle: chunk ^= (row&3)  (write==read).
#define LDS_Q   0
#define LDS_K   32768
#define LDS_V   65536
#define LDS_G   98304
#define LDS_IVD 131072
#define LDS_P   133120
#define ATTN_LDS (133120 + 8192)

__global__ __launch_bounds__(512,2) void attn_fused(const u16* __restrict__ xhat,
      const u16* __restrict__ Wallbf, const float* __restrict__ ball,
      u16* __restrict__ obuf){
  extern __shared__ char sm[];
  const int bid = blockIdx.x;
  const int h = bid & 7, r = bid >> 3;
  const int tid = threadIdx.x;
  const int w = tid >> 6;
  const int lane = tid & 63;
  const int g = lane >> 4, i = lane & 15;
  const int n0 = r * 512;
  const int sw_i = (i & 3) << 4;
  const f32x4 zf = {0.f, 0.f, 0.f, 0.f};
  const float SC = 0.17677669529663687f;  // 1/sqrt(32)

  // ================= proj =================
  {
    const int col = 16*w + i;
    const char* wb = (const char*)(Wallbf + ((size_t)(h*128 + col))*CM);
    bf16x8 B[8];
    #pragma unroll
    for(int kk=0;kk<8;kk++) B[kk] = *(const bf16x8*)(wb + kk*64 + g*16);
    const float bias = ball[h*128 + col];
    char* dst = sm + (w < 2 ? LDS_Q : w < 4 ? LDS_K : w < 6 ? LDS_V : LDS_G);
    const int clb = ((w & 1)*16)*2 + 2*i;   // byte col within 64-B row
    for(int st=0; st<32; st++){
      const char* xr = (const char*)(xhat + ((size_t)(n0 + st*16 + i))*CM);
      f32x4 acc = zf;
      #pragma unroll
      for(int kk=0;kk<8;kk++)
        acc = MFMA16(*(const bf16x8*)(xr + kk*64 + g*16), B[kk], acc);
      #pragma unroll
      for(int q=0;q<4;q++){
        float v = acc[q] + bias;
        if (w >= 6) v = 1.f/(1.f + __expf(-v));   // sigmoid gate
        int s = st*16 + 4*g + q;                  // s&3 == q
        *(u16*)(dst + s*64 + (clb ^ ((s&3)<<4))) = f2bf(v);
      }
    }
  }
  __syncthreads();

  // ================= phase A: ivd[t] =================
  {
    #pragma unroll
    for(int u=0; u<4; u++){
      int t0 = (w*4 + u)*16;
      int kr = t0 + i;
      bf16x8 ka = *(const bf16x8*)(sm + LDS_K + kr*64 + ((g*16) ^ sw_i));
      float d0=0.f,d1=0.f,d2=0.f,d3=0.f;
      for(int st=0; st<32; st++){
        int qr = st*16 + i;
        bf16x8 qf = *(const bf16x8*)(sm + LDS_Q + qr*64 + ((g*16) ^ sw_i));
        f32x4 c = MFMA16(ka, qf, zf);   // c[q] = l[s=qr][t=t0+4g+q]
        d0 += __expf(c[0]*SC); d1 += __expf(c[1]*SC);
        d2 += __expf(c[2]*SC); d3 += __expf(c[3]*SC);
      }
      #pragma unroll
      for(int off=1; off<16; off<<=1){
        d0 += __shfl_xor(d0,off); d1 += __shfl_xor(d1,off);
        d2 += __shfl_xor(d2,off); d3 += __shfl_xor(d3,off);
      }
      if (i == 0){
        float* ivd = (float*)(sm + LDS_IVD);
        ivd[t0+4*g+0] = 1.f/d0; ivd[t0+4*g+1] = 1.f/d1;
        ivd[t0+4*g+2] = 1.f/d2; ivd[t0+4*g+3] = 1.f/d3;
      }
    }
  }
  __syncthreads();

  // ================= phase B: O = P·V, gate, store =================
  {
    char* P = sm + LDS_P + w*1024;     // per-wave [16 s][16 words] swizzled
    const float* ivd = (const float*)(sm + LDS_IVD);
    bf16x8 qf[4];
    #pragma unroll
    for(int st=0; st<4; st++){
      int qr = (4*w+st)*16 + i;
      qf[st] = *(const bf16x8*)(sm + LDS_Q + qr*64 + ((g*16) ^ sw_i));
    }
    f32x4 oa[4][2];
    #pragma unroll
    for(int st=0; st<4; st++){ oa[st][0] = zf; oa[st][1] = zf; }

    for(int ts=0; ts<16; ts++){
      int t0 = ts*32;
      bf16x8 ka = *(const bf16x8*)(sm + LDS_K + (t0+i)*64    + ((g*16) ^ sw_i));
      bf16x8 kb = *(const bf16x8*)(sm + LDS_K + (t0+16+i)*64 + ((g*16) ^ sw_i));
      float v00 = ivd[t0+4*g+0],    v01 = ivd[t0+4*g+1];
      float v02 = ivd[t0+4*g+2],    v03 = ivd[t0+4*g+3];
      float v10 = ivd[t0+16+4*g+0], v11 = ivd[t0+16+4*g+1];
      float v12 = ivd[t0+16+4*g+2], v13 = ivd[t0+16+4*g+3];
      union { u16 s[8]; bf16x8 v; } vb0, vb1;   // B-frags of V, c-tiles 0/1
      #pragma unroll
      for(int e=0; e<8; e++){
        int row = t0 + 8*g + e;                 // row&3 == e&3
        int swz = (e&3)<<4;
        vb0.s[e] = *(const u16*)(sm + LDS_V + row*64 + ((2*i) ^ swz));
        vb1.s[e] = *(const u16*)(sm + LDS_V + row*64 + ((32 + 2*i) ^ swz));
      }
      #pragma unroll
      for(int st=0; st<4; st++){
        f32x4 c0 = MFMA16(ka, qf[st], zf);   // l[s][t0+4g+q]
        f32x4 c1 = MFMA16(kb, qf[st], zf);   // l[s][t0+16+4g+q]
        u32 u0 = pk2(__expf(c0[0]*SC)*v00, __expf(c0[1]*SC)*v01);
        u32 u1 = pk2(__expf(c0[2]*SC)*v02, __expf(c0[3]*SC)*v03);
        u32 u2 = pk2(__expf(c1[0]*SC)*v10, __expf(c1[1]*SC)*v11);
        u32 u3 = pk2(__expf(c1[2]*SC)*v12, __expf(c1[3]*SC)*v13);
        // P[s=i][j]: u0->words 2g,2g+1? no: u0->w=2g (j=4g,4g+1), u1->w=2g+1, u2->w=8+2g, u3->w=9+2g
        {
          int w0i = 2*g, w1i = 2*g+1, w2i = 8+2*g, w3i = 9+2*g;
          *(u32*)(P + i*64 + ((((w0i>>2) ^ (i&3))<<4) | ((w0i&3)<<2))) = u0;
          *(u32*)(P + i*64 + ((((w1i>>2) ^ (i&3))<<4) | ((w1i&3)<<2))) = u1;
          *(u32*)(P + i*64 + ((((w2i>>2) ^ (i&3))<<4) | ((w2i&3)<<2))) = u2;
          *(u32*)(P + i*64 + ((((w3i>>2) ^ (i&3))<<4) | ((w3i&3)<<2))) = u3;
        }
        bf16x8 pa = *(const bf16x8*)(P + i*64 + ((g ^ (i&3))<<4));  // A-frag P[s][t0+8g+e]
        oa[st][0] = MFMA16(pa, vb0.v, oa[st][0]);
        oa[st][1] = MFMA16(pa, vb1.v, oa[st][1]);
      }
    }
    // epilogue: gate + bf16 store
    #pragma unroll
    for(int st=0; st<4; st++){
      #pragma unroll
      for(int ct=0; ct<2; ct++){
        #pragma unroll
        for(int q=0; q<4; q++){
          int s = (4*w+st)*16 + 4*g + q;        // s&3 == q
          int cl = ct*16 + i;
          u16 gb = *(const u16*)(sm + LDS_G + s*64 + ((2*cl) ^ ((s&3)<<4)));
          float o = oa[st][ct][q] * b2f(gb);
          obuf[(size_t)(n0+s)*CM + h*32 + cl] = f2bf(o);
        }
      }
    }
  }
}

// --------------------------------------------------------------- outproj ----
// out[n -> (s,r)][m] = obuf[n][:256] · (oWhi+oWlo)[m][:256] + ob[m].  Wave = 16 rows.
__global__ __launch_bounds__(256,2) void outproj(const u16* __restrict__ obuf,
      const u16* __restrict__ oWhi, const u16* __restrict__ oWlo,
      const float* __restrict__ ob, float* __restrict__ out){
  const int tid = threadIdx.x, w = tid>>6, lane = tid&63, g = lane>>4, i = lane&15;
  const int n0 = blockIdx.x*64 + w*16;
  const char* ab = (const char*)(obuf + (size_t)(n0 + i)*CM);
  const f32x4 zf = {0.f,0.f,0.f,0.f};
  f32x4 acc[16];
  #pragma unroll
  for(int ct=0;ct<16;ct++) acc[ct] = zf;
  #pragma unroll
  for(int kk=0; kk<8; kk++){
    bf16x8 a = *(const bf16x8*)(ab + kk*64 + g*16);
    #pragma unroll
    for(int ct=0; ct<16; ct++){
      const char* wh = (const char*)(oWhi + (size_t)(ct*16 + i)*CM);
      const char* wl = (const char*)(oWlo + (size_t)(ct*16 + i)*CM);
      bf16x8 bh = *(const bf16x8*)(wh + kk*64 + g*16);
      bf16x8 bl = *(const bf16x8*)(wl + kk*64 + g*16);
      acc[ct] = MFMA16(a, bh, acc[ct]);
      acc[ct] = MFMA16(a, bl, acc[ct]);
    }
  }
  #pragma unroll
  for(int ct=0; ct<16; ct++){
    float bias = ob[ct*16 + i];
    #pragma unroll
    for(int q=0; q<4; q++){
      int n = n0 + 4*g + q;
      out[((size_t)(n & 511)*R_DIM + (n >> 9))*CM + ct*16 + i] = acc[ct][q] + bias;
    }
  }
}

// ------------------------------------------------------------------ host ----
extern "C" void kernel_launch(void* const* d_in, const int* in_sizes, int n_in,
                              void* d_out, int out_size, void* d_ws, size_t ws_size,
                              hipStream_t stream){
  const float* msa = (const float*)d_in[0];
  const float* lnw = (const float*)d_in[1];
  const float* lnb = (const float*)d_in[2];
  const float* Wq  = (const float*)d_in[3];
  const float* Wk  = (const float*)d_in[4];
  const float* Wv  = (const float*)d_in[5];
  const float* Wg  = (const float*)d_in[6];
  const float* oW  = (const float*)d_in[7];
  const float* ob  = (const float*)d_in[8];
  float* out = (float*)d_out;

  char* ws = (char*)d_ws;
  u16*   Wallbf = (u16*)(ws);
  float* ball   = (float*)(ws + 524288);
  u16*   oWhi   = (u16*)(ws + 528384);
  u16*   oWlo   = (u16*)(ws + 659456);
  u16*   xhat   = (u16*)(ws + 790528);
  u16*   obuf   = (u16*)(ws + 101453824);
  // total ws need: 202,117,120 B

  hipFuncSetAttribute((const void*)attn_fused,
                      hipFuncAttributeMaxDynamicSharedMemorySize, ATTN_LDS);

  prep_w<<<dim3(1280), dim3(64), 0, stream>>>(lnw, lnb, Wq, Wk, Wv, Wg, oW,
                                              ball, Wallbf, oWhi, oWlo);
  ln_xhat<<<dim3(NROWS/64), dim3(256), 0, stream>>>(msa, xhat);
  attn_fused<<<dim3(R_DIM*NH), dim3(512), ATTN_LDS, stream>>>(xhat, Wallbf, ball, obuf);
  outproj<<<dim3(NROWS/64), dim3(256), 0, stream>>>(obuf, oWhi, oWlo, ob, out);
}

// Round 4
// 1299.735 us; speedup vs baseline: 7.2002x; 1.2887x over previous
//
#include <hip/hip_runtime.h>
#include <hip/hip_bf16.h>

// MSAColumnAttention — R3: R2 with compile fix (__exp2f -> exp2f).
// attn_fused2: proj (D-tiles permlane-constructed into QK/PV fragment form, LDS all
// b128 conflict-free) -> phase1 d[t] -> scale V-frags by 1/d -> phase2 QK+exp+PV -> gate.
//
// 32x32x16 bf16 MFMA layouts (C/D per m74/m101; A/B by the standard gfx9 family rule):
//   A[m][k]: lane(gg,j)=gg*32+j holds row m=j, k=8gg+e (e=0..7)
//   B[k][n]: lane(gg,j) holds col n=j,        k=8gg+e
//   D[m][n]: lane(gg,j) holds col n=j, rows m=(reg&3)+8*(reg>>2)+4*gg  (reg=0..15)
// Fragment construction (algebraic, permlane32_swap: a.hi<->b.lo):
//   W[p][hh] = cvt_pk(c[4p+2hh], c[4p+2hh+1])  (8 words)
//   per T in {0,1}: (a',b') = permlane32_swap(W[2T][hh], W[2T+1][hh])
//       frag[T][hh] = a', frag[T][2+hh] = b'   -> B-frag over k = rows of D.
//
// ws layout (total 202,117,120 B):
//   Wallbf [8][128][256] bf16 @0 | ball [1024] f32 @524288 | oWhi @528384 | oWlo @659456
//   xhat [196608][256] bf16 @790528 | obuf [196608][256] bf16 @101453824

#define S_DIM 512
#define R_DIM 384
#define CM    256
#define NH    8
#define NROWS (S_DIM*R_DIM)

typedef unsigned short u16;
typedef unsigned int   u32;
typedef short bf16x8 __attribute__((ext_vector_type(8)));
typedef float f32x4  __attribute__((ext_vector_type(4)));
typedef float f32x16 __attribute__((ext_vector_type(16)));
typedef int   v2i    __attribute__((ext_vector_type(2)));

#define MFMA16(a,b,c) __builtin_amdgcn_mfma_f32_16x16x32_bf16((a),(b),(c),0,0,0)
#define MFMA32(a,b,c) __builtin_amdgcn_mfma_f32_32x32x16_bf16((a),(b),(c),0,0,0)

__device__ __forceinline__ float lo16f(u32 u){ return __uint_as_float(u << 16); }
__device__ __forceinline__ float hi16f(u32 u){ return __uint_as_float(u & 0xffff0000u); }
__device__ __forceinline__ float b2f(u16 x){ return __uint_as_float(((u32)x) << 16); }
__device__ __forceinline__ u16 f2bf(float f){
  u32 u = __float_as_uint(f);
  return (u16)((u + 0x7fffu + ((u >> 16) & 1u)) >> 16);   // RNE
}
__device__ __forceinline__ u32 pk2(float a, float b){
  return (u32)f2bf(a) | ((u32)f2bf(b) << 16);
}
__device__ __forceinline__ u32 cvtpk(float a, float b){
  u32 d;
  asm("v_cvt_pk_bf16_f32 %0, %1, %2" : "=v"(d) : "v"(a), "v"(b));
  return d;
}
__device__ __forceinline__ v2i pl32swap(u32 a, u32 b){
  return __builtin_amdgcn_permlane32_swap((int)a, (int)b, false, false);
}
__device__ __forceinline__ f32x16 zero16(){
  f32x16 z;
  #pragma unroll
  for(int q=0;q<16;q++) z[q]=0.f;
  return z;
}

// ---------------------------------------------------------------- prep_w ----
__global__ void prep_w(const float* __restrict__ lnw, const float* __restrict__ lnb,
                       const float* __restrict__ Wq, const float* __restrict__ Wk,
                       const float* __restrict__ Wv, const float* __restrict__ Wg,
                       const float* __restrict__ oW,
                       float* __restrict__ ball, u16* __restrict__ Wallbf,
                       u16* __restrict__ oWhi, u16* __restrict__ oWlo){
  int blk = blockIdx.x, t = threadIdx.x;
  if (blk < 1024){
    int h = blk >> 7, row = blk & 127, mat = row >> 5, c = row & 31;
    const float* Ws = (mat==0?Wq: mat==1?Wk: mat==2?Wv:Wg) + (size_t)(h*32+c)*CM;
    float4 w4 = ((const float4*)Ws)[t];
    float4 l4 = ((const float4*)(lnw + (size_t)h*CM))[t];
    float4 b4 = ((const float4*)(lnb + (size_t)h*CM))[t];
    ((uint2*)(Wallbf + (size_t)blk*CM))[t] =
        make_uint2(pk2(w4.x*l4.x, w4.y*l4.y), pk2(w4.z*l4.z, w4.w*l4.w));
    float p = w4.x*b4.x + w4.y*b4.y + w4.z*b4.z + w4.w*b4.w;
    #pragma unroll
    for(int off=32; off; off>>=1) p += __shfl_down(p, off);
    if(t==0) ball[blk] = p;
  } else {
    int m = blk - 1024;
    float4 w4 = ((const float4*)(oW + (size_t)m*CM))[t];
    u16 h0=f2bf(w4.x), h1=f2bf(w4.y), h2=f2bf(w4.z), h3=f2bf(w4.w);
    u16 l0=f2bf(w4.x-b2f(h0)), l1=f2bf(w4.y-b2f(h1));
    u16 l2=f2bf(w4.z-b2f(h2)), l3=f2bf(w4.w-b2f(h3));
    ((uint2*)(oWhi + (size_t)m*CM))[t] = make_uint2((u32)h0|((u32)h1<<16), (u32)h2|((u32)h3<<16));
    ((uint2*)(oWlo + (size_t)m*CM))[t] = make_uint2((u32)l0|((u32)l1<<16), (u32)l2|((u32)l3<<16));
  }
}

// ---------------------------------------------------------------- ln_xhat ----
__global__ __launch_bounds__(256) void ln_xhat(const float* __restrict__ msa,
                                               u16* __restrict__ xhat){
  const int tid = threadIdx.x;
  const int n0 = blockIdx.x*64;
  const int i = tid >> 2, p = tid & 3;
  const int n = n0 + i, rr = n >> 9, s = n & 511;
  const float* src = msa + ((size_t)s*R_DIM + rr)*CM + p*64;
  float x[64]; float sum=0.f, sq=0.f;
  #pragma unroll
  for(int j=0;j<64;j+=4){
    float4 v = *(const float4*)(src + j);
    x[j]=v.x; x[j+1]=v.y; x[j+2]=v.z; x[j+3]=v.w;
    sum += v.x+v.y+v.z+v.w;
    sq  += v.x*v.x + v.y*v.y + v.z*v.z + v.w*v.w;
  }
  sum += __shfl_xor(sum,1); sum += __shfl_xor(sum,2);
  sq  += __shfl_xor(sq,1);  sq  += __shfl_xor(sq,2);
  float mu = sum*(1.f/256.f);
  float rs = rsqrtf(sq*(1.f/256.f) - mu*mu + 1e-5f);
  u16* dst = xhat + (size_t)n*CM + p*64;
  #pragma unroll
  for(int j=0;j<64;j+=2)
    *(u32*)(dst + j) = pk2((x[j]-mu)*rs, (x[j+1]-mu)*rs);
}

// --------------------------------------------------------------- attn_fused2 ----
// LDS: Qf/Kf/Vf: [16 tile][2 T][64 lane][16B] fragment stores (32KB each)
//      Gf: [16 tile][64 lane][32B] raw D-layout gates (32KB); ivd f32[512] (2KB)
#define QF   0
#define KF   32768
#define VF   65536
#define GF   98304
#define IVD  131072
#define ATTN_LDS 133120

__global__ __launch_bounds__(512,2) void attn_fused2(const u16* __restrict__ xhat,
      const u16* __restrict__ Wallbf, const float* __restrict__ ball,
      u16* __restrict__ obuf){
  extern __shared__ char sm[];
  const int bid  = blockIdx.x;
  const int head = bid / R_DIM;          // h-major: xhat window stays L3-hot
  const int r    = bid % R_DIM;
  const int tid  = threadIdx.x;
  const int w    = tid >> 6;
  const int lane = tid & 63;
  const int gg = lane >> 5, j = lane & 31;
  const int n0 = r * 512;
  const float SC2 = 0.2550348653f;       // (1/sqrt(32)) * log2(e)

  // ================= proj: D = W·xhat^T (Q,K,G) / xhat·Wv^T (V) =================
  {
    const int mat = w >> 1, half = w & 1;
    const u16* wrow = Wallbf + ((size_t)(head*128 + mat*32 + j))*CM + gg*8;
    bf16x8 Wf[16];
    #pragma unroll
    for(int kc=0;kc<16;kc++) Wf[kc] = *(const bf16x8*)(wrow + kc*16);
    float bias16[16]; float biasv = 0.f;
    if (mat == 2) biasv = ball[head*128 + 64 + j];
    else {
      #pragma unroll
      for(int reg=0;reg<16;reg++)
        bias16[reg] = ball[head*128 + mat*32 + (reg&3) + 8*(reg>>2) + 4*gg];
    }
    char* outbase = sm + (mat==0? QF : mat==1? KF : VF);
    for(int st=0; st<8; st++){
      const int stg = half*8 + st;
      const u16* xr = xhat + ((size_t)(n0 + stg*32 + j))*CM + gg*8;
      f32x16 D = zero16();
      if (mat == 2){
        #pragma unroll
        for(int kc=0;kc<16;kc++) D = MFMA32(*(const bf16x8*)(xr + kc*16), Wf[kc], D);
      } else {
        #pragma unroll
        for(int kc=0;kc<16;kc++) D = MFMA32(Wf[kc], *(const bf16x8*)(xr + kc*16), D);
      }
      if (mat == 3){                       // G: sigmoid, store raw D-layout bf16
        u32 gw[8];
        #pragma unroll
        for(int p=0;p<4;p++)
          #pragma unroll
          for(int hh=0;hh<2;hh++){
            float a = D[4*p+2*hh]   + bias16[4*p+2*hh];
            float b = D[4*p+2*hh+1] + bias16[4*p+2*hh+1];
            float sa = 1.f/(1.f + __expf(-a));
            float sb = 1.f/(1.f + __expf(-b));
            gw[p*2+hh] = cvtpk(sa, sb);
          }
        u32* gd = (u32*)(sm + GF + ((size_t)stg*64 + lane)*32);
        *(uint4*)gd     = make_uint4(gw[0],gw[1],gw[2],gw[3]);
        *(uint4*)(gd+4) = make_uint4(gw[4],gw[5],gw[6],gw[7]);
      } else {
        if (mat == 2){
          #pragma unroll
          for(int q=0;q<16;q++) D[q] += biasv;
        } else {
          #pragma unroll
          for(int q=0;q<16;q++) D[q] += bias16[q];
        }
        u32 Wd[8];
        #pragma unroll
        for(int p=0;p<4;p++)
          #pragma unroll
          for(int hh=0;hh<2;hh++)
            Wd[p*2+hh] = cvtpk(D[4*p+2*hh], D[4*p+2*hh+1]);
        #pragma unroll
        for(int T=0;T<2;T++){
          u32 frag[4];
          #pragma unroll
          for(int hh=0;hh<2;hh++){
            v2i res = pl32swap(Wd[4*T+hh], Wd[4*T+2+hh]);
            frag[hh] = (u32)res[0]; frag[2+hh] = (u32)res[1];
          }
          *(uint4*)(outbase + ((size_t)(stg*2+T)*64 + lane)*16) =
              make_uint4(frag[0],frag[1],frag[2],frag[3]);
        }
      }
    }
  }
  __syncthreads();

  // ================= phase 1: d[t] = sum_s exp(SC*l[s,t]) ; ivd = 1/d =========
  {
    bf16x8 Kfr[2][2];
    #pragma unroll
    for(int tb=0;tb<2;tb++)
      #pragma unroll
      for(int T=0;T<2;T++)
        Kfr[tb][T] = *(const bf16x8*)(sm + KF + ((size_t)((2*w+tb)*2+T)*64 + lane)*16);
    float dacc0=0.f, dacc1=0.f;
    for(int st=0; st<16; st++){
      bf16x8 q0 = *(const bf16x8*)(sm + QF + ((size_t)(st*2+0)*64 + lane)*16);
      bf16x8 q1 = *(const bf16x8*)(sm + QF + ((size_t)(st*2+1)*64 + lane)*16);
      f32x16 A = zero16(), B = zero16();
      A = MFMA32(q0, Kfr[0][0], A); A = MFMA32(q1, Kfr[0][1], A);
      B = MFMA32(q0, Kfr[1][0], B); B = MFMA32(q1, Kfr[1][1], B);
      float s0=0.f, s1=0.f;
      #pragma unroll
      for(int q=0;q<16;q++){ s0 += exp2f(A[q]*SC2); s1 += exp2f(B[q]*SC2); }
      dacc0 += s0; dacc1 += s1;
    }
    v2i r0 = pl32swap(__float_as_uint(dacc0), __float_as_uint(dacc0));
    v2i r1 = pl32swap(__float_as_uint(dacc1), __float_as_uint(dacc1));
    float tot0 = __uint_as_float((u32)r0[0]) + __uint_as_float((u32)r0[1]);
    float tot1 = __uint_as_float((u32)r1[0]) + __uint_as_float((u32)r1[1]);
    float* ivd = (float*)(sm + IVD);
    if (lane < 32){
      ivd[(2*w+0)*32 + j] = 1.f/tot0;
      ivd[(2*w+1)*32 + j] = 1.f/tot1;
    }
  }
  __syncthreads();

  // ================= scale V-frags by ivd[t] ====================================
  {
    const float* ivd = (const float*)(sm + IVD);
    #pragma unroll
    for(int it=0; it<4; it++){
      int ch = tid + it*512;
      int t0 = (ch>>7)*32 + ((ch>>6)&1)*16 + ((ch>>5)&1)*8;
      u32* pw = (u32*)(sm + VF + (size_t)ch*16);
      uint4 v = *(uint4*)pw;
      u32 wv[4] = {v.x, v.y, v.z, v.w};
      u32 nw[4];
      #pragma unroll
      for(int rr2=0;rr2<4;rr2++){
        float lo = lo16f(wv[rr2]) * ivd[t0 + 2*rr2];
        float hi = hi16f(wv[rr2]) * ivd[t0 + 2*rr2 + 1];
        nw[rr2] = cvtpk(lo, hi);
      }
      *(uint4*)pw = make_uint4(nw[0],nw[1],nw[2],nw[3]);
    }
  }
  __syncthreads();

  // ================= phase 2: O^T = Vt^T · exp(L^T) ; gate; store ==============
  {
    bf16x8 Qfr[2][2];
    #pragma unroll
    for(int sb=0;sb<2;sb++)
      #pragma unroll
      for(int T=0;T<2;T++)
        Qfr[sb][T] = *(const bf16x8*)(sm + QF + ((size_t)((2*w+sb)*2+T)*64 + lane)*16);
    f32x16 O[2]; O[0] = zero16(); O[1] = zero16();
    for(int tt=0; tt<16; tt++){
      bf16x8 Kt0 = *(const bf16x8*)(sm + KF + ((size_t)(tt*2+0)*64 + lane)*16);
      bf16x8 Kt1 = *(const bf16x8*)(sm + KF + ((size_t)(tt*2+1)*64 + lane)*16);
      bf16x8 Vt0 = *(const bf16x8*)(sm + VF + ((size_t)(tt*2+0)*64 + lane)*16);
      bf16x8 Vt1 = *(const bf16x8*)(sm + VF + ((size_t)(tt*2+1)*64 + lane)*16);
      #pragma unroll
      for(int sb=0;sb<2;sb++){
        f32x16 D = zero16();
        D = MFMA32(Kt0, Qfr[sb][0], D);      // D[t'][s'] accumulate over c
        D = MFMA32(Kt1, Qfr[sb][1], D);
        u32 Wd[8];
        #pragma unroll
        for(int p=0;p<4;p++)
          #pragma unroll
          for(int hh=0;hh<2;hh++)
            Wd[p*2+hh] = cvtpk(exp2f(D[4*p+2*hh]*SC2), exp2f(D[4*p+2*hh+1]*SC2));
        union { u32 wu[4]; bf16x8 v; } pf0, pf1;
        #pragma unroll
        for(int hh=0;hh<2;hh++){
          v2i res = pl32swap(Wd[0+hh], Wd[2+hh]);
          pf0.wu[hh] = (u32)res[0]; pf0.wu[2+hh] = (u32)res[1];
          v2i res2 = pl32swap(Wd[4+hh], Wd[6+hh]);
          pf1.wu[hh] = (u32)res2[0]; pf1.wu[2+hh] = (u32)res2[1];
        }
        O[sb] = MFMA32(Vt0, pf0.v, O[sb]);
        O[sb] = MFMA32(Vt1, pf1.v, O[sb]);
      }
    }
    // epilogue: gate + bf16 store
    #pragma unroll
    for(int sb=0;sb<2;sb++){
      int stg = 2*w + sb;
      const u32* gd = (const u32*)(sm + GF + ((size_t)stg*64 + lane)*32);
      uint4 ga = *(const uint4*)gd, gb = *(const uint4*)(gd+4);
      u32 g[8] = {ga.x,ga.y,ga.z,ga.w, gb.x,gb.y,gb.z,gb.w};
      int srow = n0 + stg*32 + j;
      u32* ob32 = (u32*)(obuf + (size_t)srow*CM + head*32);
      #pragma unroll
      for(int p=0;p<4;p++)
        #pragma unroll
        for(int hh=0;hh<2;hh++){
          float o0 = O[sb][4*p+2*hh]   * lo16f(g[p*2+hh]);
          float o1 = O[sb][4*p+2*hh+1] * hi16f(g[p*2+hh]);
          ob32[4*p + 2*gg + hh] = cvtpk(o0, o1);
        }
    }
  }
}

// --------------------------------------------------------------- outproj ----
__global__ __launch_bounds__(256,2) void outproj(const u16* __restrict__ obuf,
      const u16* __restrict__ oWhi, const u16* __restrict__ oWlo,
      const float* __restrict__ ob, float* __restrict__ out){
  const int tid = threadIdx.x, w = tid>>6, lane = tid&63, g = lane>>4, i = lane&15;
  const int n0 = blockIdx.x*64 + w*16;
  const char* ab = (const char*)(obuf + (size_t)(n0 + i)*CM);
  const f32x4 zf = {0.f,0.f,0.f,0.f};
  f32x4 acc[16];
  #pragma unroll
  for(int ct=0;ct<16;ct++) acc[ct] = zf;
  #pragma unroll
  for(int kk=0; kk<8; kk++){
    bf16x8 a = *(const bf16x8*)(ab + kk*64 + g*16);
    #pragma unroll
    for(int ct=0; ct<16; ct++){
      const char* wh = (const char*)(oWhi + (size_t)(ct*16 + i)*CM);
      const char* wl = (const char*)(oWlo + (size_t)(ct*16 + i)*CM);
      bf16x8 bh = *(const bf16x8*)(wh + kk*64 + g*16);
      bf16x8 bl = *(const bf16x8*)(wl + kk*64 + g*16);
      acc[ct] = MFMA16(a, bh, acc[ct]);
      acc[ct] = MFMA16(a, bl, acc[ct]);
    }
  }
  #pragma unroll
  for(int ct=0; ct<16; ct++){
    float bias = ob[ct*16 + i];
    #pragma unroll
    for(int q=0; q<4; q++){
      int n = n0 + 4*g + q;
      out[((size_t)(n & 511)*R_DIM + (n >> 9))*CM + ct*16 + i] = acc[ct][q] + bias;
    }
  }
}

// ------------------------------------------------------------------ host ----
extern "C" void kernel_launch(void* const* d_in, const int* in_sizes, int n_in,
                              void* d_out, int out_size, void* d_ws, size_t ws_size,
                              hipStream_t stream){
  const float* msa = (const float*)d_in[0];
  const float* lnw = (const float*)d_in[1];
  const float* lnb = (const float*)d_in[2];
  const float* Wq  = (const float*)d_in[3];
  const float* Wk  = (const float*)d_in[4];
  const float* Wv  = (const float*)d_in[5];
  const float* Wg  = (const float*)d_in[6];
  const float* oW  = (const float*)d_in[7];
  const float* ob  = (const float*)d_in[8];
  float* out = (float*)d_out;

  char* ws = (char*)d_ws;
  u16*   Wallbf = (u16*)(ws);
  float* ball   = (float*)(ws + 524288);
  u16*   oWhi   = (u16*)(ws + 528384);
  u16*   oWlo   = (u16*)(ws + 659456);
  u16*   xhat   = (u16*)(ws + 790528);
  u16*   obuf   = (u16*)(ws + 101453824);

  (void)hipFuncSetAttribute((const void*)attn_fused2,
                      hipFuncAttributeMaxDynamicSharedMemorySize, ATTN_LDS);

  prep_w<<<dim3(1280), dim3(64), 0, stream>>>(lnw, lnb, Wq, Wk, Wv, Wg, oW,
                                              ball, Wallbf, oWhi, oWlo);
  ln_xhat<<<dim3(NROWS/64), dim3(256), 0, stream>>>(msa, xhat);
  attn_fused2<<<dim3(R_DIM*NH), dim3(512), ATTN_LDS, stream>>>(xhat, Wallbf, ball, obuf);
  outproj<<<dim3(NROWS/64), dim3(256), 0, stream>>>(obuf, oWhi, oWlo, ob, out);
}